// Round 1
// baseline (15807.605 us; speedup 1.0000x reference)
//
#include <hip/hip_runtime.h>

#define UNITS   2048
#define IN_DIM  128
#define T_STEPS 4096
#define NBLK    256   // one block per CU, each owns 8 units
#define TPB     256
#define ROWS    8     // units per block
#define KCH     8     // k-chunk per thread

typedef unsigned int u32;
typedef u32 u32x4 __attribute__((ext_vector_type(4)));
typedef u32 u32x2 __attribute__((ext_vector_type(2)));

// Re-initialize the communication buffer every call (harness replays the graph;
// we must not depend on leftover state). Separate dispatch => ordering + visibility.
__global__ void esn_init(const float* __restrict__ s0, u32x2* __restrict__ buf) {
    int i = blockIdx.x * blockDim.x + threadIdx.x;
    if (i < UNITS) {
        u32x2 a; a[0] = __float_as_uint(s0[i]); a[1] = 0u;       // s_0, tag 0
        buf[i] = a;
        u32x2 b; b[0] = 0u; b[1] = 0xFFFFFFFFu;                  // parity-1: invalid tag
        buf[UNITS + i] = b;
    }
}

__global__ void __launch_bounds__(TPB, 1) esn_step(
    const float* __restrict__ inp,   // [4096][128]
    const float* __restrict__ s0,    // [2048]
    const float* __restrict__ W,     // [2048][2048] row-major, pre[j] = sum_k W[j][k]*s[k]
    const float* __restrict__ Win,   // [2048][128]
    float* __restrict__ out,         // [4096*2048 + 2048]
    u32x2* __restrict__ buf)         // [2][2048] (value, step-tag) pairs
{
    const int b    = blockIdx.x;
    const int tid  = threadIdx.x;
    const int lane = tid & 63;
    const int wv   = tid >> 6;

    // ---- W fragment in registers: rows b*8..b*8+7, cols tid*8..tid*8+7 (64 VGPRs) ----
    float w[ROWS][KCH];
    {
        const float* wp = W + (size_t)(b * ROWS) * UNITS + tid * KCH;
        #pragma unroll
        for (int r = 0; r < ROWS; ++r) {
            float4 lo = *(const float4*)(wp + (size_t)r * UNITS);
            float4 hi = *(const float4*)(wp + (size_t)r * UNITS + 4);
            w[r][0] = lo.x; w[r][1] = lo.y; w[r][2] = lo.z; w[r][3] = lo.w;
            w[r][4] = hi.x; w[r][5] = hi.y; w[r][6] = hi.z; w[r][7] = hi.w;
        }
    }
    // ---- Win fragment (wave 0 only): lane holds input cols {2*lane, 2*lane+1} ----
    float win0[ROWS], win1[ROWS];
    #pragma unroll
    for (int r = 0; r < ROWS; ++r) { win0[r] = 0.f; win1[r] = 0.f; }
    if (wv == 0) {
        const float* wip = Win + (size_t)(b * ROWS) * IN_DIM + lane * 2;
        #pragma unroll
        for (int r = 0; r < ROWS; ++r) {
            float2 v = *(const float2*)(wip + r * IN_DIM);
            win0[r] = v.x; win1[r] = v.y;
        }
    }

    float s_old = (tid < ROWS) ? s0[b * ROWS + tid] : 0.f;

    __shared__ float red[2][4][ROWS];   // parity-double-buffered cross-wave partials

    const u32x2* base0 = buf;
    const u32x2* base1 = buf + UNITS;

    for (int t = 0; t < T_STEPS; ++t) {
        // input drive for step t (plain cached load; hidden under the poll)
        float u0 = 0.f, u1 = 0.f;
        if (wv == 0) {
            float2 uu = *(const float2*)(inp + (size_t)t * IN_DIM + lane * 2);
            u0 = uu.x; u1 = uu.y;
        }

        // ---- poll: thread tid consumes block tid's 8 (val,tag) pairs (64B) ----
        const u32x2* pp = ((t & 1) ? base1 : base0) + tid * KCH;
        u32x4 A, B, C, D;
        const u32 tag = (u32)t;
        while (true) {
            asm volatile(
                "global_load_dwordx4 %0, %4, off sc0 sc1\n\t"
                "global_load_dwordx4 %1, %4, off offset:16 sc0 sc1\n\t"
                "global_load_dwordx4 %2, %4, off offset:32 sc0 sc1\n\t"
                "global_load_dwordx4 %3, %4, off offset:48 sc0 sc1\n\t"
                "s_waitcnt vmcnt(0)"
                : "=v"(A), "=v"(B), "=v"(C), "=v"(D)
                : "v"(pp)
                : "memory");
            bool ok = (A[1] == tag) & (A[3] == tag) & (B[1] == tag) & (B[3] == tag)
                    & (C[1] == tag) & (C[3] == tag) & (D[1] == tag) & (D[3] == tag);
            if (ok) break;
        }
        float sv[KCH];
        sv[0] = __uint_as_float(A[0]); sv[1] = __uint_as_float(A[2]);
        sv[2] = __uint_as_float(B[0]); sv[3] = __uint_as_float(B[2]);
        sv[4] = __uint_as_float(C[0]); sv[5] = __uint_as_float(C[2]);
        sv[6] = __uint_as_float(D[0]); sv[7] = __uint_as_float(D[2]);

        // ---- partial matvec: 64 FMAs, 8 independent chains ----
        float acc[ROWS];
        #pragma unroll
        for (int r = 0; r < ROWS; ++r) {
            float a = 0.f;
            #pragma unroll
            for (int k = 0; k < KCH; ++k) a = fmaf(w[r][k], sv[k], a);
            acc[r] = a;
        }
        if (wv == 0) {
            #pragma unroll
            for (int r = 0; r < ROWS; ++r)
                acc[r] = fmaf(win0[r], u0, fmaf(win1[r], u1, acc[r]));
        }

        // ---- 64-lane xor butterfly (every lane ends with the wave total) ----
        #pragma unroll
        for (int m = 1; m < 64; m <<= 1) {
            #pragma unroll
            for (int r = 0; r < ROWS; ++r)
                acc[r] += __shfl_xor(acc[r], m, 64);
        }

        const int par = t & 1;
        if (lane < ROWS) red[par][wv][lane] = acc[lane];
        __syncthreads();

        if (tid < ROWS) {
            float pre = red[par][0][tid] + red[par][1][tid]
                      + red[par][2][tid] + red[par][3][tid];
            // tanh(x) = 1 - 2/(exp(2x)+1); saturates correctly at +/-inf
            float e  = __expf(2.0f * pre);
            float th = 1.0f - 2.0f / (e + 1.0f);
            float sn = 0.9f * s_old + 0.1f * th;
            s_old = sn;
            const int j = b * ROWS + tid;
            out[(size_t)t * UNITS + j] = sn;                       // history[t] = s_{t+1}
            if (t == T_STEPS - 1) out[(size_t)T_STEPS * UNITS + j] = sn;  // final state
            // publish (value, tag=t+1) atomically as one 8B write-through store
            u32x2 vt; vt[0] = __float_as_uint(sn); vt[1] = (u32)(t + 1);
            u32x2* ps = (u32x2*)((((t + 1) & 1) ? base1 : base0) + j);
            asm volatile("global_store_dwordx2 %0, %1, off sc0 sc1"
                         :: "v"(ps), "v"(vt) : "memory");
        }
    }
}

extern "C" void kernel_launch(void* const* d_in, const int* in_sizes, int n_in,
                              void* d_out, int out_size, void* d_ws, size_t ws_size,
                              hipStream_t stream) {
    const float* inp = (const float*)d_in[0];   // input_sequence [4096,128]
    const float* s0  = (const float*)d_in[1];   // initial_state  [1,2048]
    const float* W   = (const float*)d_in[2];   // W   [2048,2048]
    const float* Win = (const float*)d_in[3];   // Win [2048,128]
    float* out = (float*)d_out;
    u32x2* buf = (u32x2*)d_ws;                  // 2*2048*8 = 32 KiB scratch

    esn_init<<<dim3(UNITS / 256), dim3(256), 0, stream>>>(s0, buf);

    void* args[6];
    args[0] = (void*)&inp; args[1] = (void*)&s0;  args[2] = (void*)&W;
    args[3] = (void*)&Win; args[4] = (void*)&out; args[5] = (void*)&buf;
    hipLaunchCooperativeKernel((void*)esn_step, dim3(NBLK), dim3(TPB), args, 0, stream);
}

// Round 2
// 15721.530 us; speedup vs baseline: 1.0055x; 1.0055x over previous
//
#include <hip/hip_runtime.h>

#define UNITS   2048
#define IN_DIM  128
#define T_STEPS 4096
#define NBLK    64    // 64 consumer blocks: 4x less broadcast fabric traffic
#define TPB     1024
#define BROWS   32    // units (rows) per block
#define GROUPS  4     // row groups per block (tid>>8)
#define GROWS   8     // rows per group
#define KCH     8     // cols per thread
#define CSTR    256   // col stride between a thread's cols

typedef unsigned int u32;
typedef u32 u32x4 __attribute__((ext_vector_type(4)));
typedef u32 u32x2 __attribute__((ext_vector_type(2)));

// Re-initialize the communication buffer every call (graph replay must not
// depend on leftover state). Separate dispatch => ordering + visibility.
__global__ void esn_init(const float* __restrict__ s0, u32x2* __restrict__ buf) {
    int i = blockIdx.x * blockDim.x + threadIdx.x;
    if (i < UNITS) {
        u32x2 a; a[0] = __float_as_uint(s0[i]); a[1] = 0u;       // s_0, tag 0
        buf[i] = a;
        u32x2 b; b[0] = 0u; b[1] = 0xFFFFFFFFu;                  // parity-1: invalid tag
        buf[UNITS + i] = b;
    }
}

__global__ void __launch_bounds__(TPB, 4) esn_step(
    const float* __restrict__ inp,   // [4096][128]
    const float* __restrict__ s0,    // [2048]
    const float* __restrict__ W,     // [2048][2048] row-major
    const float* __restrict__ Win,   // [2048][128]
    float* __restrict__ out,         // [4096*2048 + 2048]
    u32x2* __restrict__ buf)         // [2][2048] (value, step-tag) pairs
{
    const int b    = blockIdx.x;
    const int tid  = threadIdx.x;
    const int c    = tid & 255;      // col id: this thread's cols are c + 256*j
    const int g    = tid >> 8;       // row group 0..3
    const int lane = tid & 63;
    const int wv   = tid >> 6;       // wave 0..15

    // ---- W fragment in registers: rows row0..row0+7, cols c+256*j (64 VGPRs) ----
    const int row0 = b * BROWS + g * GROWS;
    float w[GROWS][KCH];
    #pragma unroll
    for (int r = 0; r < GROWS; ++r) {
        const float* wp = W + (size_t)(row0 + r) * UNITS + c;
        #pragma unroll
        for (int j = 0; j < KCH; ++j) w[r][j] = wp[j * CSTR];   // coalesced per (r,j)
    }
    // ---- Win fragment: thread with c<128 owns input col c for its 8 rows ----
    float winv[GROWS];
    #pragma unroll
    for (int r = 0; r < GROWS; ++r) winv[r] = 0.f;
    if (c < IN_DIM) {
        #pragma unroll
        for (int r = 0; r < GROWS; ++r)
            winv[r] = Win[(size_t)(row0 + r) * IN_DIM + c];
    }

    float s_old = (tid < BROWS) ? s0[b * BROWS + tid] : 0.f;

    __shared__ float sv_lds[2][UNITS];        // parity-buffered state vector
    __shared__ float red[2][16][GROWS];       // parity-buffered wave partials

    const u32x2* base0 = buf;
    const u32x2* base1 = buf + UNITS;

    for (int t = 0; t < T_STEPS; ++t) {
        const int par = t & 1;

        // input drive for step t (plain cached load, independent of poll)
        float u = 0.f;
        if (c < IN_DIM) u = inp[(size_t)t * IN_DIM + c];

        // ---- poll: threads 0..255 each consume 8 (val,tag) pairs (64B) ----
        if (tid < 256) {
            const u32x2* pp = (par ? base1 : base0) + tid * KCH;
            u32x4 A, B, C, D;
            const u32 tag = (u32)t;
            while (true) {
                asm volatile(
                    "global_load_dwordx4 %0, %4, off sc0 sc1\n\t"
                    "global_load_dwordx4 %1, %4, off offset:16 sc0 sc1\n\t"
                    "global_load_dwordx4 %2, %4, off offset:32 sc0 sc1\n\t"
                    "global_load_dwordx4 %3, %4, off offset:48 sc0 sc1\n\t"
                    "s_waitcnt vmcnt(0)"
                    : "=v"(A), "=v"(B), "=v"(C), "=v"(D)
                    : "v"(pp)
                    : "memory");
                bool ok = (A[1] == tag) & (A[3] == tag) & (B[1] == tag) & (B[3] == tag)
                        & (C[1] == tag) & (C[3] == tag) & (D[1] == tag) & (D[3] == tag);
                if (ok) break;
            }
            float4* dst = (float4*)&sv_lds[par][tid * KCH];
            float4 v0, v1;
            v0.x = __uint_as_float(A[0]); v0.y = __uint_as_float(A[2]);
            v0.z = __uint_as_float(B[0]); v0.w = __uint_as_float(B[2]);
            v1.x = __uint_as_float(C[0]); v1.y = __uint_as_float(C[2]);
            v1.z = __uint_as_float(D[0]); v1.w = __uint_as_float(D[2]);
            dst[0] = v0; dst[1] = v1;
        }
        __syncthreads();

        // ---- operands from LDS (lane-stride 4B: conflict-free) ----
        float sv[KCH];
        #pragma unroll
        for (int j = 0; j < KCH; ++j) sv[j] = sv_lds[par][c + j * CSTR];

        // ---- partial matvec: 64 FMAs, 8 independent chains ----
        float acc[GROWS];
        #pragma unroll
        for (int r = 0; r < GROWS; ++r) {
            float a = 0.f;
            #pragma unroll
            for (int k = 0; k < KCH; ++k) a = fmaf(w[r][k], sv[k], a);
            acc[r] = a;
        }
        if (c < IN_DIM) {
            #pragma unroll
            for (int r = 0; r < GROWS; ++r) acc[r] = fmaf(winv[r], u, acc[r]);
        }

        // ---- 64-lane xor butterfly (every lane ends with the wave total) ----
        #pragma unroll
        for (int m = 1; m < 64; m <<= 1) {
            #pragma unroll
            for (int r = 0; r < GROWS; ++r)
                acc[r] += __shfl_xor(acc[r], m, 64);
        }
        if (lane < GROWS) red[par][wv][lane] = acc[lane];
        __syncthreads();

        // ---- finalize: 32 threads combine 4 waves of their group, publish ----
        if (tid < BROWS) {
            const int gg = tid >> 3, rr = tid & 7;
            float pre = red[par][gg * 4 + 0][rr] + red[par][gg * 4 + 1][rr]
                      + red[par][gg * 4 + 2][rr] + red[par][gg * 4 + 3][rr];
            // tanh(x) = 1 - 2/(exp(2x)+1); saturates correctly at +/-inf
            float e  = __expf(2.0f * pre);
            float th = 1.0f - 2.0f / (e + 1.0f);
            float sn = 0.9f * s_old + 0.1f * th;
            s_old = sn;
            const int j = b * BROWS + tid;
            out[(size_t)t * UNITS + j] = sn;                            // history
            if (t == T_STEPS - 1) out[(size_t)T_STEPS * UNITS + j] = sn; // final state
            u32x2 vt; vt[0] = __float_as_uint(sn); vt[1] = (u32)(t + 1);
            u32x2* ps = (u32x2*)((((t + 1) & 1) ? base1 : base0) + j);
            asm volatile("global_store_dwordx2 %0, %1, off sc0 sc1"
                         :: "v"(ps), "v"(vt) : "memory");
        }
    }
}

extern "C" void kernel_launch(void* const* d_in, const int* in_sizes, int n_in,
                              void* d_out, int out_size, void* d_ws, size_t ws_size,
                              hipStream_t stream) {
    const float* inp = (const float*)d_in[0];   // input_sequence [4096,128]
    const float* s0  = (const float*)d_in[1];   // initial_state  [1,2048]
    const float* W   = (const float*)d_in[2];   // W   [2048,2048]
    const float* Win = (const float*)d_in[3];   // Win [2048,128]
    float* out = (float*)d_out;
    u32x2* buf = (u32x2*)d_ws;                  // 2*2048*8 = 32 KiB scratch

    esn_init<<<dim3(UNITS / 256), dim3(256), 0, stream>>>(s0, buf);

    void* args[6];
    args[0] = (void*)&inp; args[1] = (void*)&s0;  args[2] = (void*)&W;
    args[3] = (void*)&Win; args[4] = (void*)&out; args[5] = (void*)&buf;
    hipLaunchCooperativeKernel((void*)esn_step, dim3(NBLK), dim3(TPB), args, 0, stream);
}

// Round 3
// 10304.788 us; speedup vs baseline: 1.5340x; 1.5257x over previous
//
#include <hip/hip_runtime.h>

#define UNITS   2048
#define IN_DIM  128
#define T_STEPS 4096
#define NBLK    64
#define TPB     1024
#define BROWS   32    // rows per block
#define GROWS   8     // rows per thread-group
#define KCH     8     // cols per thread
#define CSTR    256   // col stride between a thread's cols

typedef unsigned int u32;
typedef u32 u32x4 __attribute__((ext_vector_type(4)));
typedef u32 u32x2 __attribute__((ext_vector_type(2)));

// Reset pair tags so stale tags from a previous graph replay can never match.
// Tag 0 is never polled (first poll looks for tag 1).
__global__ void esn_init(u32x2* __restrict__ buf) {
    int i = blockIdx.x * blockDim.x + threadIdx.x;
    if (i < 2 * UNITS) { u32x2 z; z[0] = 0u; z[1] = 0u; buf[i] = z; }
}

template <int CTRL>
__device__ __forceinline__ float dpp_add(float x) {
    int y = __builtin_amdgcn_update_dpp(0, __float_as_int(x), CTRL, 0xF, 0xF, true);
    return x + __int_as_float(y);
}

__global__ void __launch_bounds__(TPB, 1) esn_step(
    const float* __restrict__ inp,   // [4096][128]
    const float* __restrict__ s0,    // [2048]
    const float* __restrict__ W,     // [2048][2048] row-major
    const float* __restrict__ Win,   // [2048][128]
    float* __restrict__ out,         // [4096*2048 + 2048]
    u32x2* __restrict__ buf)         // [2][2048] (value, step-tag) pairs
{
    const int b    = blockIdx.x;
    const int tid  = threadIdx.x;
    const int c    = tid & 255;      // col id: this thread's cols are c + 256*j
    const int g    = tid >> 8;       // row group 0..3
    const int lane = tid & 63;
    const int wv   = tid >> 6;       // wave 0..15

    // ---- W fragment in registers: rows row0..row0+7, cols c+256*j (64 VGPRs) ----
    const int row0 = b * BROWS + g * GROWS;
    float w[GROWS][KCH];
    #pragma unroll
    for (int r = 0; r < GROWS; ++r) {
        const float* wp = W + (size_t)(row0 + r) * UNITS + c;
        #pragma unroll
        for (int j = 0; j < KCH; ++j) w[r][j] = wp[j * CSTR];
    }
    float winv[GROWS];
    #pragma unroll
    for (int r = 0; r < GROWS; ++r) winv[r] = 0.f;
    if (c < IN_DIM) {
        #pragma unroll
        for (int r = 0; r < GROWS; ++r)
            winv[r] = Win[(size_t)(row0 + r) * IN_DIM + c];
    }

    float s_old = (tid < BROWS) ? s0[b * BROWS + tid] : 0.f;

    __shared__ float sv_lds[2][UNITS];          // parity-buffered state vector
    __shared__ float red[2][16][4][GROWS];      // per-wave, per-row16 partials
    __shared__ u32 cnt_sv[2];                   // monotone poller-deposit counters
    __shared__ u32 cnt_red[2];                  // monotone wave-partial counters

    // ---- pre-loop: local deposit of s_0 (no comm needed for step 0) ----
    if (tid < 256) {
        float4 a  = *(const float4*)(s0 + tid * 8);
        float4 bb = *(const float4*)(s0 + tid * 8 + 4);
        *(float4*)&sv_lds[0][tid * 8]     = a;
        *(float4*)&sv_lds[0][tid * 8 + 4] = bb;
    }
    if (tid == 0) { cnt_sv[0] = 4u; cnt_sv[1] = 0u; cnt_red[0] = 0u; cnt_red[1] = 0u; }
    __syncthreads();   // one-time only

    for (int t = 0; t < T_STEPS; ++t) {
        const int par   = t & 1;
        const u32 epoch = (u32)(t >> 1) + 1u;

        // input drive for step t (issue before the spin to hide latency)
        float u = 0.f;
        if (c < IN_DIM) u = inp[(size_t)t * IN_DIM + c];

        // ---- wait for sv[par] = s_t (poller waves spin tight; others back off) ----
        if (wv >= 4) {
            while (__hip_atomic_load(&cnt_sv[par], __ATOMIC_ACQUIRE,
                                     __HIP_MEMORY_SCOPE_WORKGROUP) < 4u * epoch)
                __builtin_amdgcn_s_sleep(1);
        } else {
            while (__hip_atomic_load(&cnt_sv[par], __ATOMIC_ACQUIRE,
                                     __HIP_MEMORY_SCOPE_WORKGROUP) < 4u * epoch) {}
        }

        // ---- operands from LDS (lane-consecutive: conflict-free) ----
        float sv[KCH];
        #pragma unroll
        for (int j = 0; j < KCH; ++j) sv[j] = sv_lds[par][c + j * CSTR];

        // ---- partial matvec: 64 FMAs ----
        float acc[GROWS];
        #pragma unroll
        for (int r = 0; r < GROWS; ++r) {
            float a = 0.f;
            #pragma unroll
            for (int k = 0; k < KCH; ++k) a = fmaf(w[r][k], sv[k], a);
            acc[r] = a;
        }
        if (c < IN_DIM) {
            #pragma unroll
            for (int r = 0; r < GROWS; ++r) acc[r] = fmaf(winv[r], u, acc[r]);
        }

        // ---- reduce across 16 lanes via VALU DPP (no LDS pipe) ----
        #pragma unroll
        for (int r = 0; r < GROWS; ++r) {
            acc[r] = dpp_add<0xB1>(acc[r]);    // xor 1 (quad_perm)
            acc[r] = dpp_add<0x4E>(acc[r]);    // xor 2 (quad_perm)
            acc[r] = dpp_add<0x141>(acc[r]);   // +other quad (row_half_mirror)
            acc[r] = dpp_add<0x140>(acc[r]);   // +other 8 (row_mirror)
        }
        // deposit per-row16 partials: lanes with (lane&15)<8 write acc[lane&7]
        if ((lane & 15) < 8) {
            float v = acc[0];                  // static-select acc[lane&7] (no scratch)
            #pragma unroll
            for (int r = 1; r < GROWS; ++r) v = ((lane & 7) == r) ? acc[r] : v;
            red[par][wv][lane >> 4][lane & 7] = v;
        }
        if (lane == 0)
            __hip_atomic_fetch_add(&cnt_red[par], 1u, __ATOMIC_RELEASE,
                                   __HIP_MEMORY_SCOPE_WORKGROUP);

        // ---- finalize: 32 threads combine 16 partials, publish immediately ----
        if (tid < BROWS) {
            while (__hip_atomic_load(&cnt_red[par], __ATOMIC_ACQUIRE,
                                     __HIP_MEMORY_SCOPE_WORKGROUP) < 16u * epoch) {}
            const int gg = tid >> 3, rr = tid & 7;
            float pre = 0.f;
            #pragma unroll
            for (int q = 0; q < 4; ++q)
                #pragma unroll
                for (int h = 0; h < 4; ++h)
                    pre += red[par][4 * gg + q][h][rr];
            float e  = __expf(2.0f * pre);
            float th = 1.0f - 2.0f / (e + 1.0f);
            float sn = 0.9f * s_old + 0.1f * th;
            s_old = sn;
            const int j = b * BROWS + tid;
            out[(size_t)t * UNITS + j] = sn;
            if (t == T_STEPS - 1) {
                out[(size_t)T_STEPS * UNITS + j] = sn;
            } else {
                u32x2 vt; vt[0] = __float_as_uint(sn); vt[1] = (u32)(t + 1);
                u32x2* ps = buf + ((t + 1) & 1) * UNITS + j;
                asm volatile("global_store_dwordx2 %0, %1, off sc0 sc1"
                             :: "v"(ps), "v"(vt) : "memory");
            }
        }

        // ---- pollers gather s_{t+1} for the next iteration ----
        if (wv < 4 && t < T_STEPS - 1) {
            const int pnx = (t + 1) & 1;
            const u32 tag = (u32)(t + 1);
            const u32x2* pp = buf + pnx * UNITS + tid * KCH;
            u32x4 A, B, C, D;
            while (true) {
                asm volatile(
                    "global_load_dwordx4 %0, %4, off sc0 sc1\n\t"
                    "global_load_dwordx4 %1, %4, off offset:16 sc0 sc1\n\t"
                    "global_load_dwordx4 %2, %4, off offset:32 sc0 sc1\n\t"
                    "global_load_dwordx4 %3, %4, off offset:48 sc0 sc1\n\t"
                    "s_waitcnt vmcnt(0)"
                    : "=v"(A), "=v"(B), "=v"(C), "=v"(D)
                    : "v"(pp)
                    : "memory");
                bool ok = (A[1] == tag) & (A[3] == tag) & (B[1] == tag) & (B[3] == tag)
                        & (C[1] == tag) & (C[3] == tag) & (D[1] == tag) & (D[3] == tag);
                if (ok) break;
            }
            float4 v0, v1;
            v0.x = __uint_as_float(A[0]); v0.y = __uint_as_float(A[2]);
            v0.z = __uint_as_float(B[0]); v0.w = __uint_as_float(B[2]);
            v1.x = __uint_as_float(C[0]); v1.y = __uint_as_float(C[2]);
            v1.z = __uint_as_float(D[0]); v1.w = __uint_as_float(D[2]);
            float4* dst = (float4*)&sv_lds[pnx][tid * KCH];
            dst[0] = v0; dst[1] = v1;
            if (lane == 0)
                __hip_atomic_fetch_add(&cnt_sv[pnx], 1u, __ATOMIC_RELEASE,
                                       __HIP_MEMORY_SCOPE_WORKGROUP);
        }
    }
}

extern "C" void kernel_launch(void* const* d_in, const int* in_sizes, int n_in,
                              void* d_out, int out_size, void* d_ws, size_t ws_size,
                              hipStream_t stream) {
    const float* inp = (const float*)d_in[0];   // input_sequence [4096,128]
    const float* s0  = (const float*)d_in[1];   // initial_state  [1,2048]
    const float* W   = (const float*)d_in[2];   // W   [2048,2048]
    const float* Win = (const float*)d_in[3];   // Win [2048,128]
    float* out = (float*)d_out;
    u32x2* buf = (u32x2*)d_ws;                  // 2*2048*8 = 32 KiB scratch

    esn_init<<<dim3(16), dim3(256), 0, stream>>>(buf);

    void* args[6];
    args[0] = (void*)&inp; args[1] = (void*)&s0;  args[2] = (void*)&W;
    args[3] = (void*)&Win; args[4] = (void*)&out; args[5] = (void*)&buf;
    hipLaunchCooperativeKernel((void*)esn_step, dim3(NBLK), dim3(TPB), args, 0, stream);
}